// Round 4
// baseline (521.733 us; speedup 1.0000x reference)
//
#include <hip/hip_runtime.h>

// ---------------------------------------------------------------------------
// 2-layer GCN forward, pull-mode, bf16 gather tables.
//
// R4 change: deg/cursor tables padded to one entry per 64B cache line
// (stride 16 ints).  R3 evidence: 1.6M atomics on a 400KB table ran at
// 13 G atomic/s vs 78 G/s on a 51MB table (R1) -> memory-side atomic units
// serialize per LINE, not per address.  Padding removes the 256-per-line
// pileup.
//
// ws layout (4-byte units): dinv[N] | degP[N*16] | rowptr[N+4] |
//   cursorP[N*16] | bsum[128] | csr_src[E] |
//   h ushort[N*128] (reused as h2 ushort[N*64]) | h1 float[N*128]
// ---------------------------------------------------------------------------

typedef unsigned int uint;
typedef unsigned short ushort;

#define PAD 4  // log2(16) - pad stride in ints (64B line)

__device__ inline ushort f2bf(float f) {
    uint u = __float_as_uint(f);
    return (ushort)((u + 0x7fffu + ((u >> 16) & 1u)) >> 16);  // RNE
}
__device__ inline float bf_lo(uint u) { return __uint_as_float(u << 16); }
__device__ inline float bf_hi(uint u) { return __uint_as_float(u & 0xffff0000u); }

// 4 edges per thread, atomics on line-padded deg table
__global__ void deg_count_kernel(const int* __restrict__ tgt, int* __restrict__ degP, int E) {
    int t = blockIdx.x * blockDim.x + threadIdx.x;
    int base = t * 4;
    if (base + 3 < E) {
        int4 v = *(const int4*)&tgt[base];
        atomicAdd(&degP[(size_t)v.x << PAD], 1);
        atomicAdd(&degP[(size_t)v.y << PAD], 1);
        atomicAdd(&degP[(size_t)v.z << PAD], 1);
        atomicAdd(&degP[(size_t)v.w << PAD], 1);
    } else {
        for (int k = base; k < E; ++k) atomicAdd(&degP[(size_t)tgt[k] << PAD], 1);
    }
}

// ---- scan over padded deg -> rowptr (exclusive) + cursor init + dinv ----
__global__ __launch_bounds__(256) void scan_partial(const int* __restrict__ degP,
                                                    int* __restrict__ bsum, int N) {
    int t = threadIdx.x, b = blockIdx.x;
    int base = b * 1024 + t * 4;
    int s = 0;
#pragma unroll
    for (int k = 0; k < 4; ++k) s += (base + k < N) ? degP[(size_t)(base + k) << PAD] : 0;
#pragma unroll
    for (int off = 32; off > 0; off >>= 1) s += __shfl_down(s, off, 64);
    __shared__ int ws[4];
    if ((t & 63) == 0) ws[t >> 6] = s;
    __syncthreads();
    if (t == 0) bsum[b] = ws[0] + ws[1] + ws[2] + ws[3];
}

__global__ void scan_bsum(int* __restrict__ bsum, int nb) {
    __shared__ int s[128];
    int t = threadIdx.x;  // 128 threads
    int v = (t < nb) ? bsum[t] : 0;
    s[t] = v;
    __syncthreads();
    for (int off = 1; off < 128; off <<= 1) {
        int u = (t >= off) ? s[t - off] : 0;
        __syncthreads();
        s[t] += u;
        __syncthreads();
    }
    if (t < nb) bsum[t] = s[t] - v;  // exclusive
}

__global__ __launch_bounds__(256) void scan_final(const int* __restrict__ degP,
                                                  const int* __restrict__ bsum,
                                                  int* __restrict__ rowptr,
                                                  int* __restrict__ cursorP,
                                                  float* __restrict__ dinv, int N, int E) {
    int t = threadIdx.x, b = blockIdx.x;
    int base = b * 1024 + t * 4;
    int d[4];
#pragma unroll
    for (int k = 0; k < 4; ++k) d[k] = (base + k < N) ? degP[(size_t)(base + k) << PAD] : 0;
    int tot = d[0] + d[1] + d[2] + d[3];
    int incl = tot;
    int lane = t & 63, wid = t >> 6;
#pragma unroll
    for (int off = 1; off < 64; off <<= 1) {
        int u = __shfl_up(incl, off, 64);
        if (lane >= off) incl += u;
    }
    __shared__ int wsum[4];
    if (lane == 63) wsum[wid] = incl;
    __syncthreads();
    int woff = 0;
    for (int w = 0; w < wid; ++w) woff += wsum[w];
    int run = incl - tot + woff + bsum[b];
#pragma unroll
    for (int k = 0; k < 4; ++k) {
        if (base + k < N) {
            rowptr[base + k] = run;
            cursorP[(size_t)(base + k) << PAD] = run;
            dinv[base + k] = rsqrtf((float)d[k] + 1.0f);  // +1 self-loop
        }
        run += d[k];
    }
    if (b == gridDim.x - 1 && t == 255) rowptr[N] = E;
}

__global__ void fill_csr(const int* __restrict__ src, const int* __restrict__ tgt,
                         int* __restrict__ cursorP, int* __restrict__ csr_src, int E) {
    int t = blockIdx.x * blockDim.x + threadIdx.x;
    if (t < E) {
        int pos = atomicAdd(&cursorP[(size_t)tgt[t] << PAD], 1);
        csr_src[pos] = src[t];
    }
}

// ---- C[N,M](bf16) = A[N,128](fp32) @ W[128,M](fp32); 4x4 fp32 microtile ----
template <int M, int ROWS>
__global__ __launch_bounds__(256) void gemm_fp32(const float* __restrict__ A,
                                                 const float* __restrict__ W,
                                                 ushort* __restrict__ C, int N) {
    __shared__ float wS[64 * M];
    __shared__ float aT[64 * ROWS];
    const int tid  = threadIdx.x;
    const int row0 = blockIdx.x * ROWS;
    const int c4   = (tid % (M / 4)) * 4;
    const int r0   = (tid / (M / 4)) * 4;
    float acc[4][4] = {};

    for (int kt = 0; kt < 128; kt += 64) {
        for (int i = tid * 4; i < 64 * M; i += 256 * 4)
            *(float4*)&wS[i] = *(const float4*)&W[(kt + i / M) * M + (i % M)];
        for (int i = tid * 4; i < ROWS * 64; i += 256 * 4) {
            int r = i / 64, k = i % 64;
            int row = row0 + r;
            if (row >= N) row = N - 1;
            float4 a = *(const float4*)&A[row * 128 + kt + k];
            aT[(k + 0) * ROWS + r] = a.x;
            aT[(k + 1) * ROWS + r] = a.y;
            aT[(k + 2) * ROWS + r] = a.z;
            aT[(k + 3) * ROWS + r] = a.w;
        }
        __syncthreads();
#pragma unroll 16
        for (int k = 0; k < 64; ++k) {
            float4 av = *(const float4*)&aT[k * ROWS + r0];
            float4 wv = *(const float4*)&wS[k * M + c4];
            float a4[4] = {av.x, av.y, av.z, av.w};
            float w4[4] = {wv.x, wv.y, wv.z, wv.w};
#pragma unroll
            for (int i = 0; i < 4; ++i)
#pragma unroll
                for (int j = 0; j < 4; ++j) acc[i][j] += a4[i] * w4[j];
        }
        __syncthreads();
    }
#pragma unroll
    for (int i = 0; i < 4; ++i) {
        int row = row0 + r0 + i;
        if (row < N) {
            ushort4 v;
            v.x = f2bf(acc[i][0]); v.y = f2bf(acc[i][1]);
            v.z = f2bf(acc[i][2]); v.w = f2bf(acc[i][3]);
            *(ushort4*)&C[(size_t)row * M + c4] = v;
        }
    }
}

// ---- pull gather, bf16 table.  Q=D/8 lanes per row, G=64/Q edge slots. ----
template <int D, bool RELU>
__global__ __launch_bounds__(256) void gather_kernel(
    const ushort* __restrict__ h, const int* __restrict__ rowptr,
    const int* __restrict__ csr_src, const float* __restrict__ dinv,
    const float* __restrict__ bias, float* __restrict__ out, int N) {
    constexpr int Q = D / 8;   // lanes covering one row (16B bf16x8 per lane)
    constexpr int G = 64 / Q;  // concurrent edge slots per wave
    const int wid = threadIdx.x >> 6, lane = threadIdx.x & 63;
    const int node = blockIdx.x * 4 + wid;
    if (node >= N) return;
    const int g = lane / Q, q = lane % Q;
    const int qoff = q * 8;
    const int beg = rowptr[node], end = rowptr[node + 1];
    float acc[8] = {};

    for (int j = beg; j < end; j += 2 * G) {  // 2 independent chains in flight
        int e0 = j + g, e1 = j + G + g;
        {
            bool v = e0 < end;
            int s = v ? csr_src[e0] : node;
            float w = v ? dinv[s] : 0.0f;
            uint4 hv = *(const uint4*)&h[(size_t)s * D + qoff];
            acc[0] += w * bf_lo(hv.x); acc[1] += w * bf_hi(hv.x);
            acc[2] += w * bf_lo(hv.y); acc[3] += w * bf_hi(hv.y);
            acc[4] += w * bf_lo(hv.z); acc[5] += w * bf_hi(hv.z);
            acc[6] += w * bf_lo(hv.w); acc[7] += w * bf_hi(hv.w);
        }
        {
            bool v = e1 < end;
            int s = v ? csr_src[e1] : node;
            float w = v ? dinv[s] : 0.0f;
            uint4 hv = *(const uint4*)&h[(size_t)s * D + qoff];
            acc[0] += w * bf_lo(hv.x); acc[1] += w * bf_hi(hv.x);
            acc[2] += w * bf_lo(hv.y); acc[3] += w * bf_hi(hv.y);
            acc[4] += w * bf_lo(hv.z); acc[5] += w * bf_hi(hv.z);
            acc[6] += w * bf_lo(hv.w); acc[7] += w * bf_hi(hv.w);
        }
    }
    // reduce across the G edge slots
#pragma unroll
    for (int m = Q; m < 64; m <<= 1)
#pragma unroll
        for (int k = 0; k < 8; ++k) acc[k] += __shfl_xor(acc[k], m, 64);

    const float di = dinv[node];
    {   // self-loop
        uint4 hv = *(const uint4*)&h[(size_t)node * D + qoff];
        acc[0] += di * bf_lo(hv.x); acc[1] += di * bf_hi(hv.x);
        acc[2] += di * bf_lo(hv.y); acc[3] += di * bf_hi(hv.y);
        acc[4] += di * bf_lo(hv.z); acc[5] += di * bf_hi(hv.z);
        acc[6] += di * bf_lo(hv.w); acc[7] += di * bf_hi(hv.w);
    }
    if (g == 0) {
        float4 b0 = *(const float4*)&bias[qoff];
        float4 b1 = *(const float4*)&bias[qoff + 4];
        float r[8] = {di * acc[0] + b0.x, di * acc[1] + b0.y,
                      di * acc[2] + b0.z, di * acc[3] + b0.w,
                      di * acc[4] + b1.x, di * acc[5] + b1.y,
                      di * acc[6] + b1.z, di * acc[7] + b1.w};
        if (RELU) {
#pragma unroll
            for (int k = 0; k < 8; ++k) r[k] = fmaxf(r[k], 0.0f);
        }
        *(float4*)&out[(size_t)node * D + qoff]     = make_float4(r[0], r[1], r[2], r[3]);
        *(float4*)&out[(size_t)node * D + qoff + 4] = make_float4(r[4], r[5], r[6], r[7]);
    }
}

extern "C" void kernel_launch(void* const* d_in, const int* in_sizes, int n_in,
                              void* d_out, int out_size, void* d_ws, size_t ws_size,
                              hipStream_t stream) {
    const float* x  = (const float*)d_in[0];
    const int*   ei = (const int*)d_in[1];
    const float* W1 = (const float*)d_in[2];
    const float* b1 = (const float*)d_in[3];
    const float* W2 = (const float*)d_in[4];
    const float* b2 = (const float*)d_in[5];
    float* out = (float*)d_out;

    const int N = in_sizes[0] / 128;
    const int E = in_sizes[1] / 2;
    const int* src = ei;
    const int* tgt = ei + E;

    float* ws = (float*)d_ws;
    const size_t Np = (size_t)((N + 3) & ~3);
    float*  dinv    = ws;                        // Np
    int*    degP    = (int*)(ws + Np);           // Np*16  (line-padded)
    int*    rowptr  = degP + (Np << PAD);        // Np+4
    int*    cursorP = rowptr + Np + 4;           // Np*16  (line-padded)
    int*    bsum    = cursorP + (Np << PAD);     // 128
    int*    csr_src = bsum + 128;                // E
    ushort* h       = (ushort*)(csr_src + E);    // N*128 bf16 (reused as h2: N*64)
    float*  h1      = (float*)(h + (size_t)N * 128);  // N*128 fp32
    ushort* h2      = h;

    const int nb = (N + 1023) / 1024;

    hipMemsetAsync(degP, 0, ((size_t)N << PAD) * sizeof(int), stream);
    deg_count_kernel<<<(E / 4 + 255) / 256, 256, 0, stream>>>(tgt, degP, E);
    scan_partial<<<nb, 256, 0, stream>>>(degP, bsum, N);
    scan_bsum<<<1, 128, 0, stream>>>(bsum, nb);
    scan_final<<<nb, 256, 0, stream>>>(degP, bsum, rowptr, cursorP, dinv, N, E);
    fill_csr<<<(E + 255) / 256, 256, 0, stream>>>(src, tgt, cursorP, csr_src, E);

    // Layer 1
    gemm_fp32<128, 32><<<(N + 31) / 32, 256, 0, stream>>>(x, W1, h, N);
    gather_kernel<128, true><<<(N + 3) / 4, 256, 0, stream>>>(
        h, rowptr, csr_src, dinv, b1, h1, N);

    // Layer 2
    gemm_fp32<64, 64><<<(N + 63) / 64, 256, 0, stream>>>(h1, W2, h2, N);
    gather_kernel<64, false><<<(N + 3) / 4, 256, 0, stream>>>(
        h2, rowptr, csr_src, dinv, b2, out, N);
}

// Round 5
// 397.429 us; speedup vs baseline: 1.3128x; 1.3128x over previous
//
#include <hip/hip_runtime.h>

// ---------------------------------------------------------------------------
// 2-layer GCN forward, pull-mode, bf16 gather tables.
//
// R5: atomic-free CSR build (R4 evidence: returning global atomics run at
// 12.8 G/s vs 78 G/s non-returning; scattered 4B stores cause 105MB of
// full-line writebacks).  Two-level counting sort on tgt>>8:
//   hist (LDS) -> scan -> bucket_scatter (LDS cursors, int2 tmp)
//   -> bucket_deg (LDS) -> scan (rowptr+dinv) -> bucket_fill (LDS cursors)
// Zero global atomics in the whole pipeline.
//
// ws (4B units): dinv[Np] deg[Np] rowptr[Np+4] counts[512*256] bsum[128]
//   csr_src[E] tmp int2[E] | h ushort[N*128] (reused as h2) | h1 float[N*128]
// ---------------------------------------------------------------------------

typedef unsigned int uint;
typedef unsigned short ushort;

#define BSHIFT 8          // nodes per bucket = 256
#define MAXBK  512        // max buckets (N <= 131072)
#define NB     256        // hist/scatter blocks

__device__ inline ushort f2bf(float f) {
    uint u = __float_as_uint(f);
    return (ushort)((u + 0x7fffu + ((u >> 16) & 1u)) >> 16);  // RNE
}
__device__ inline float bf_lo(uint u) { return __uint_as_float(u << 16); }
__device__ inline float bf_hi(uint u) { return __uint_as_float(u & 0xffff0000u); }

// ---- pass 1: per-block bucket histogram (LDS atomics only) ----
__global__ __launch_bounds__(256) void hist_kernel(const int* __restrict__ tgt,
                                                   int* __restrict__ counts,
                                                   int E, int chunk, int nbk) {
    __shared__ int hist[MAXBK];
    int t = threadIdx.x, b = blockIdx.x;
    for (int i = t; i < nbk; i += 256) hist[i] = 0;
    __syncthreads();
    int s = b * chunk, e = min(E, s + chunk);
    for (int i = s + t; i < e; i += 256) atomicAdd(&hist[tgt[i] >> BSHIFT], 1);
    __syncthreads();
    for (int i = t; i < nbk; i += 256) counts[i * NB + b] = hist[i];
}

// ---- generic 3-kernel exclusive scan (M <= 128*1024) ----
__global__ __launch_bounds__(256) void scan_partial(const int* __restrict__ in,
                                                    int* __restrict__ bsum, int M) {
    int t = threadIdx.x, b = blockIdx.x;
    int base = b * 1024 + t * 4;
    int s = 0;
#pragma unroll
    for (int k = 0; k < 4; ++k) s += (base + k < M) ? in[base + k] : 0;
#pragma unroll
    for (int off = 32; off > 0; off >>= 1) s += __shfl_down(s, off, 64);
    __shared__ int ws[4];
    if ((t & 63) == 0) ws[t >> 6] = s;
    __syncthreads();
    if (t == 0) bsum[b] = ws[0] + ws[1] + ws[2] + ws[3];
}

__global__ void scan_bsum(int* __restrict__ bsum, int nb) {
    __shared__ int s[128];
    int t = threadIdx.x;  // 128 threads
    int v = (t < nb) ? bsum[t] : 0;
    s[t] = v;
    __syncthreads();
    for (int off = 1; off < 128; off <<= 1) {
        int u = (t >= off) ? s[t - off] : 0;
        __syncthreads();
        s[t] += u;
        __syncthreads();
    }
    if (t < nb) bsum[t] = s[t] - v;  // exclusive
}

// DEG=true: also write dinv + tail out[M]=total (rowptr[N]=E)
template <bool DEG>
__global__ __launch_bounds__(256) void scan_final_k(const int* __restrict__ in,
                                                    const int* __restrict__ bsum,
                                                    int* __restrict__ out,
                                                    float* __restrict__ dinv,
                                                    int M, int total) {
    int t = threadIdx.x, b = blockIdx.x;
    int base = b * 1024 + t * 4;
    int d[4];
#pragma unroll
    for (int k = 0; k < 4; ++k) d[k] = (base + k < M) ? in[base + k] : 0;
    int tot = d[0] + d[1] + d[2] + d[3];
    int incl = tot;
    int lane = t & 63, wid = t >> 6;
#pragma unroll
    for (int off = 1; off < 64; off <<= 1) {
        int u = __shfl_up(incl, off, 64);
        if (lane >= off) incl += u;
    }
    __shared__ int wsum[4];
    if (lane == 63) wsum[wid] = incl;
    __syncthreads();
    int woff = 0;
    for (int w = 0; w < wid; ++w) woff += wsum[w];
    int run = incl - tot + woff + bsum[b];
#pragma unroll
    for (int k = 0; k < 4; ++k) {
        if (base + k < M) {
            out[base + k] = run;
            if (DEG) dinv[base + k] = rsqrtf((float)d[k] + 1.0f);  // +1 self-loop
        }
        run += d[k];
    }
    if (DEG && b == gridDim.x - 1 && t == 255) out[M] = total;
}

// ---- pass 2: scatter edges into bucket-contiguous tmp (LDS cursors) ----
__global__ __launch_bounds__(256) void bucket_scatter(const int* __restrict__ src,
                                                      const int* __restrict__ tgt,
                                                      const int* __restrict__ offsets,
                                                      int2* __restrict__ tmp,
                                                      int E, int chunk, int nbk) {
    __shared__ int cur[MAXBK];
    int t = threadIdx.x, b = blockIdx.x;
    for (int i = t; i < nbk; i += 256) cur[i] = offsets[i * NB + b];
    __syncthreads();
    int s = b * chunk, e = min(E, s + chunk);
    for (int i = s + t; i < e; i += 256) {
        int tg = tgt[i];
        int p = atomicAdd(&cur[tg >> BSHIFT], 1);
        tmp[p] = make_int2(src[i], tg);
    }
}

// ---- pass 3: per-bucket node-degree histogram (replaces global deg_count) ----
__global__ __launch_bounds__(256) void bucket_deg(const int2* __restrict__ tmp,
                                                  const int* __restrict__ offsets,
                                                  int* __restrict__ deg,
                                                  int N, int E, int nbk) {
    __shared__ int cnt[256];
    int t = threadIdx.x, b = blockIdx.x;
    cnt[t] = 0;
    __syncthreads();
    int s = offsets[b * NB];
    int e = (b + 1 < nbk) ? offsets[(b + 1) * NB] : E;
    for (int i = s + t; i < e; i += 256) atomicAdd(&cnt[tmp[i].y & 255], 1);
    __syncthreads();
    int node = b * 256 + t;
    if (node < N) deg[node] = cnt[t];
}

// ---- pass 4: fill csr_src within bucket (LDS cursors, 16KB write window) ----
__global__ __launch_bounds__(256) void bucket_fill(const int2* __restrict__ tmp,
                                                   const int* __restrict__ rowptr,
                                                   int* __restrict__ csr_src, int N) {
    __shared__ int cur[256];
    int t = threadIdx.x, b = blockIdx.x;
    int base = b * 256;
    int node = base + t;
    if (node < N) cur[t] = rowptr[node];
    __syncthreads();
    int s = rowptr[base];
    int e = rowptr[min(base + 256, N)];
    for (int i = s + t; i < e; i += 256) {
        int2 ed = tmp[i];
        int p = atomicAdd(&cur[ed.y & 255], 1);
        csr_src[p] = ed.x;
    }
}

// ---- C[N,M](bf16) = A[N,128](fp32) @ W[128,M](fp32); 4x4 fp32 microtile ----
template <int M, int ROWS>
__global__ __launch_bounds__(256) void gemm_fp32(const float* __restrict__ A,
                                                 const float* __restrict__ W,
                                                 ushort* __restrict__ C, int N) {
    __shared__ float wS[64 * M];
    __shared__ float aT[64 * ROWS];
    const int tid  = threadIdx.x;
    const int row0 = blockIdx.x * ROWS;
    const int c4   = (tid % (M / 4)) * 4;
    const int r0   = (tid / (M / 4)) * 4;
    float acc[4][4] = {};

    for (int kt = 0; kt < 128; kt += 64) {
        for (int i = tid * 4; i < 64 * M; i += 256 * 4)
            *(float4*)&wS[i] = *(const float4*)&W[(kt + i / M) * M + (i % M)];
        for (int i = tid * 4; i < ROWS * 64; i += 256 * 4) {
            int r = i / 64, k = i % 64;
            int row = row0 + r;
            if (row >= N) row = N - 1;
            float4 a = *(const float4*)&A[row * 128 + kt + k];
            aT[(k + 0) * ROWS + r] = a.x;
            aT[(k + 1) * ROWS + r] = a.y;
            aT[(k + 2) * ROWS + r] = a.z;
            aT[(k + 3) * ROWS + r] = a.w;
        }
        __syncthreads();
#pragma unroll 16
        for (int k = 0; k < 64; ++k) {
            float4 av = *(const float4*)&aT[k * ROWS + r0];
            float4 wv = *(const float4*)&wS[k * M + c4];
            float a4[4] = {av.x, av.y, av.z, av.w};
            float w4[4] = {wv.x, wv.y, wv.z, wv.w};
#pragma unroll
            for (int i = 0; i < 4; ++i)
#pragma unroll
                for (int j = 0; j < 4; ++j) acc[i][j] += a4[i] * w4[j];
        }
        __syncthreads();
    }
#pragma unroll
    for (int i = 0; i < 4; ++i) {
        int row = row0 + r0 + i;
        if (row < N) {
            ushort4 v;
            v.x = f2bf(acc[i][0]); v.y = f2bf(acc[i][1]);
            v.z = f2bf(acc[i][2]); v.w = f2bf(acc[i][3]);
            *(ushort4*)&C[(size_t)row * M + c4] = v;
        }
    }
}

// ---- pull gather, bf16 table.  Q=D/8 lanes per row, G=64/Q edge slots. ----
template <int D, bool RELU>
__global__ __launch_bounds__(256) void gather_kernel(
    const ushort* __restrict__ h, const int* __restrict__ rowptr,
    const int* __restrict__ csr_src, const float* __restrict__ dinv,
    const float* __restrict__ bias, float* __restrict__ out, int N) {
    constexpr int Q = D / 8;   // lanes covering one row (16B bf16x8 per lane)
    constexpr int G = 64 / Q;  // concurrent edge slots per wave
    const int wid = threadIdx.x >> 6, lane = threadIdx.x & 63;
    const int node = blockIdx.x * 4 + wid;
    if (node >= N) return;
    const int g = lane / Q, q = lane % Q;
    const int qoff = q * 8;
    const int beg = rowptr[node], end = rowptr[node + 1];
    float acc[8] = {};

    for (int j = beg; j < end; j += 2 * G) {  // 2 independent chains in flight
        int e0 = j + g, e1 = j + G + g;
        {
            bool v = e0 < end;
            int s = v ? csr_src[e0] : node;
            float w = v ? dinv[s] : 0.0f;
            uint4 hv = *(const uint4*)&h[(size_t)s * D + qoff];
            acc[0] += w * bf_lo(hv.x); acc[1] += w * bf_hi(hv.x);
            acc[2] += w * bf_lo(hv.y); acc[3] += w * bf_hi(hv.y);
            acc[4] += w * bf_lo(hv.z); acc[5] += w * bf_hi(hv.z);
            acc[6] += w * bf_lo(hv.w); acc[7] += w * bf_hi(hv.w);
        }
        {
            bool v = e1 < end;
            int s = v ? csr_src[e1] : node;
            float w = v ? dinv[s] : 0.0f;
            uint4 hv = *(const uint4*)&h[(size_t)s * D + qoff];
            acc[0] += w * bf_lo(hv.x); acc[1] += w * bf_hi(hv.x);
            acc[2] += w * bf_lo(hv.y); acc[3] += w * bf_hi(hv.y);
            acc[4] += w * bf_lo(hv.z); acc[5] += w * bf_hi(hv.z);
            acc[6] += w * bf_lo(hv.w); acc[7] += w * bf_hi(hv.w);
        }
    }
    // reduce across the G edge slots
#pragma unroll
    for (int m = Q; m < 64; m <<= 1)
#pragma unroll
        for (int k = 0; k < 8; ++k) acc[k] += __shfl_xor(acc[k], m, 64);

    const float di = dinv[node];
    {   // self-loop
        uint4 hv = *(const uint4*)&h[(size_t)node * D + qoff];
        acc[0] += di * bf_lo(hv.x); acc[1] += di * bf_hi(hv.x);
        acc[2] += di * bf_lo(hv.y); acc[3] += di * bf_hi(hv.y);
        acc[4] += di * bf_lo(hv.z); acc[5] += di * bf_hi(hv.z);
        acc[6] += di * bf_lo(hv.w); acc[7] += di * bf_hi(hv.w);
    }
    if (g == 0) {
        float4 b0 = *(const float4*)&bias[qoff];
        float4 b1 = *(const float4*)&bias[qoff + 4];
        float r[8] = {di * acc[0] + b0.x, di * acc[1] + b0.y,
                      di * acc[2] + b0.z, di * acc[3] + b0.w,
                      di * acc[4] + b1.x, di * acc[5] + b1.y,
                      di * acc[6] + b1.z, di * acc[7] + b1.w};
        if (RELU) {
#pragma unroll
            for (int k = 0; k < 8; ++k) r[k] = fmaxf(r[k], 0.0f);
        }
        *(float4*)&out[(size_t)node * D + qoff]     = make_float4(r[0], r[1], r[2], r[3]);
        *(float4*)&out[(size_t)node * D + qoff + 4] = make_float4(r[4], r[5], r[6], r[7]);
    }
}

extern "C" void kernel_launch(void* const* d_in, const int* in_sizes, int n_in,
                              void* d_out, int out_size, void* d_ws, size_t ws_size,
                              hipStream_t stream) {
    const float* x  = (const float*)d_in[0];
    const int*   ei = (const int*)d_in[1];
    const float* W1 = (const float*)d_in[2];
    const float* b1 = (const float*)d_in[3];
    const float* W2 = (const float*)d_in[4];
    const float* b2 = (const float*)d_in[5];
    float* out = (float*)d_out;

    const int N = in_sizes[0] / 128;
    const int E = in_sizes[1] / 2;
    const int* src = ei;
    const int* tgt = ei + E;

    const int nbk   = (N + 255) >> BSHIFT;       // buckets
    const int chunk = (E + NB - 1) / NB;         // edges per hist/scatter block
    const int Mc    = nbk * NB;                  // counts array length

    float* ws = (float*)d_ws;
    const size_t Np = (size_t)((N + 3) & ~3);
    float*  dinv    = ws;                           // Np
    int*    deg     = (int*)(ws + Np);              // Np
    int*    rowptr  = deg + Np;                     // Np+4
    int*    counts  = rowptr + Np + 4;              // MAXBK*NB (scanned in place)
    int*    bsum    = counts + MAXBK * NB;          // 128
    int*    csr_src = bsum + 128;                   // E
    int2*   tmp     = (int2*)(csr_src + E);         // E int2
    ushort* h       = (ushort*)(tmp + E);           // N*128 bf16 (reused as h2)
    float*  h1      = (float*)(h + (size_t)N * 128);  // N*128 fp32
    ushort* h2      = h;

    const int nbc = (Mc + 1023) / 1024;  // scan blocks for counts
    const int nbd = (N + 1023) / 1024;   // scan blocks for deg

    // CSR build — no global atomics
    hist_kernel<<<NB, 256, 0, stream>>>(tgt, counts, E, chunk, nbk);
    scan_partial<<<nbc, 256, 0, stream>>>(counts, bsum, Mc);
    scan_bsum<<<1, 128, 0, stream>>>(bsum, nbc);
    scan_final_k<false><<<nbc, 256, 0, stream>>>(counts, bsum, counts, nullptr, Mc, E);
    bucket_scatter<<<NB, 256, 0, stream>>>(src, tgt, counts, tmp, E, chunk, nbk);
    bucket_deg<<<nbk, 256, 0, stream>>>(tmp, counts, deg, N, E, nbk);
    scan_partial<<<nbd, 256, 0, stream>>>(deg, bsum, N);
    scan_bsum<<<1, 128, 0, stream>>>(bsum, nbd);
    scan_final_k<true><<<nbd, 256, 0, stream>>>(deg, bsum, rowptr, dinv, N, E);
    bucket_fill<<<nbk, 256, 0, stream>>>(tmp, rowptr, csr_src, N);

    // Layer 1
    gemm_fp32<128, 32><<<(N + 31) / 32, 256, 0, stream>>>(x, W1, h, N);
    gather_kernel<128, true><<<(N + 3) / 4, 256, 0, stream>>>(
        h, rowptr, csr_src, dinv, b1, h1, N);

    // Layer 2
    gemm_fp32<64, 64><<<(N + 63) / 64, 256, 0, stream>>>(h1, W2, h2, N);
    gather_kernel<64, false><<<(N + 3) / 4, 256, 0, stream>>>(
        h2, rowptr, csr_src, dinv, b2, out, N);
}

// Round 6
// 335.116 us; speedup vs baseline: 1.5569x; 1.1859x over previous
//
#include <hip/hip_runtime.h>

// ---------------------------------------------------------------------------
// 2-layer GCN forward, pull-mode, bf16 tables, MFMA GEMMs.
//
// R6: (a) GEMMs moved to v_mfma_f32_16x16x32_bf16 (A from global fp32,
// converted in-flight; W^T staged bf16 in LDS with +8 pad). (b) CSR build
// slimmed: tmp packed to (src<<8)|(tgt&255), bsum-scan fused into
// scan_final_counts, deg-scan prefixes taken from scanned counts (bucket
// boundaries) -> 7 build kernels, no global atomics anywhere.
//
// ws (4B units): dinv[Np] deg[Np] rowptr[Np+4] counts[MAXBK*NB] bsum[128]
//   csr_src[E] tmpP[E] | h ushort[N*128] (reused as h2) | h1 float[N*128]
// ---------------------------------------------------------------------------

typedef unsigned int uint;
typedef unsigned short ushort;
typedef __attribute__((ext_vector_type(8))) short bf16x8;
typedef __attribute__((ext_vector_type(4))) float f32x4;

#define BSHIFT 8          // nodes per bucket = 256
#define MAXBK  512        // max buckets (N <= 131072)
#define NB     256        // hist/scatter blocks

__device__ inline ushort f2bf(float f) {
    uint u = __float_as_uint(f);
    return (ushort)((u + 0x7fffu + ((u >> 16) & 1u)) >> 16);  // RNE
}
__device__ inline float bf_lo(uint u) { return __uint_as_float(u << 16); }
__device__ inline float bf_hi(uint u) { return __uint_as_float(u & 0xffff0000u); }

// ---- pass 1: per-block bucket histogram (LDS atomics only) ----
__global__ __launch_bounds__(256) void hist_kernel(const int* __restrict__ tgt,
                                                   int* __restrict__ counts,
                                                   int E, int chunk, int nbk) {
    __shared__ int hist[MAXBK];
    int t = threadIdx.x, b = blockIdx.x;
    for (int i = t; i < nbk; i += 256) hist[i] = 0;
    __syncthreads();
    int s = b * chunk, e = min(E, s + chunk);
    for (int i = s + t; i < e; i += 256) atomicAdd(&hist[tgt[i] >> BSHIFT], 1);
    __syncthreads();
    for (int i = t; i < nbk; i += 256) counts[i * NB + b] = hist[i];
}

// ---- scan step 1: per-1024 partial sums of counts ----
__global__ __launch_bounds__(256) void scan_partial(const int* __restrict__ in,
                                                    int* __restrict__ bsum, int M) {
    int t = threadIdx.x, b = blockIdx.x;
    int base = b * 1024 + t * 4;
    int s = 0;
#pragma unroll
    for (int k = 0; k < 4; ++k) s += (base + k < M) ? in[base + k] : 0;
#pragma unroll
    for (int off = 32; off > 0; off >>= 1) s += __shfl_down(s, off, 64);
    __shared__ int ws[4];
    if ((t & 63) == 0) ws[t >> 6] = s;
    __syncthreads();
    if (t == 0) bsum[b] = ws[0] + ws[1] + ws[2] + ws[3];
}

// ---- scan step 2: exclusive scan of counts in place (bsum prefix fused) ----
__global__ __launch_bounds__(256) void scan_final_counts(int* __restrict__ counts,
                                                         const int* __restrict__ bsum,
                                                         int M) {
    int t = threadIdx.x, b = blockIdx.x;
    int lane = t & 63, wid = t >> 6;
    int p = 0;
    for (int i = t; i < b; i += 256) p += bsum[i];
#pragma unroll
    for (int off = 32; off > 0; off >>= 1) p += __shfl_down(p, off, 64);
    __shared__ int ps[4];
    if (lane == 0) ps[wid] = p;
    __syncthreads();
    int pre = ps[0] + ps[1] + ps[2] + ps[3];

    int base = b * 1024 + t * 4;
    int d[4];
#pragma unroll
    for (int k = 0; k < 4; ++k) d[k] = (base + k < M) ? counts[base + k] : 0;
    int tot = d[0] + d[1] + d[2] + d[3];
    int incl = tot;
#pragma unroll
    for (int off = 1; off < 64; off <<= 1) {
        int u = __shfl_up(incl, off, 64);
        if (lane >= off) incl += u;
    }
    __shared__ int wsum[4];
    if (lane == 63) wsum[wid] = incl;
    __syncthreads();
    int woff = 0;
    for (int w = 0; w < wid; ++w) woff += wsum[w];
    int run = incl - tot + woff + pre;
#pragma unroll
    for (int k = 0; k < 4; ++k) {
        if (base + k < M) counts[base + k] = run;
        run += d[k];
    }
}

// ---- pass 2: scatter edges into bucket-contiguous packed tmp ----
__global__ __launch_bounds__(256) void bucket_scatter(const int* __restrict__ src,
                                                      const int* __restrict__ tgt,
                                                      const int* __restrict__ offsets,
                                                      int* __restrict__ tmpP,
                                                      int E, int chunk, int nbk) {
    __shared__ int cur[MAXBK];
    int t = threadIdx.x, b = blockIdx.x;
    for (int i = t; i < nbk; i += 256) cur[i] = offsets[i * NB + b];
    __syncthreads();
    int s = b * chunk, e = min(E, s + chunk);
    for (int i = s + t; i < e; i += 256) {
        int tg = tgt[i];
        int p = atomicAdd(&cur[tg >> BSHIFT], 1);
        tmpP[p] = (src[i] << BSHIFT) | (tg & 255);
    }
}

// ---- pass 3: per-bucket node-degree histogram ----
__global__ __launch_bounds__(256) void bucket_deg(const int* __restrict__ tmpP,
                                                  const int* __restrict__ offsets,
                                                  int* __restrict__ deg,
                                                  int N, int E, int nbk) {
    __shared__ int cnt[256];
    int t = threadIdx.x, b = blockIdx.x;
    cnt[t] = 0;
    __syncthreads();
    int s = offsets[b * NB];
    int e = (b + 1 < nbk) ? offsets[(b + 1) * NB] : E;
    for (int i = s + t; i < e; i += 256) atomicAdd(&cnt[tmpP[i] & 255], 1);
    __syncthreads();
    int node = b * 256 + t;
    if (node < N) deg[node] = cnt[t];
}

// ---- deg -> rowptr (exclusive) + dinv; block prefix read from offsets ----
__global__ __launch_bounds__(256) void scan_final_deg(const int* __restrict__ deg,
                                                      const int* __restrict__ offsets,
                                                      int* __restrict__ rowptr,
                                                      float* __restrict__ dinv,
                                                      int N, int E) {
    int t = threadIdx.x, b = blockIdx.x;
    int lane = t & 63, wid = t >> 6;
    int pre = offsets[(4 * b) * NB];  // edges before bucket 4b (nodes 1024b..)
    int base = b * 1024 + t * 4;
    int d[4];
#pragma unroll
    for (int k = 0; k < 4; ++k) d[k] = (base + k < N) ? deg[base + k] : 0;
    int tot = d[0] + d[1] + d[2] + d[3];
    int incl = tot;
#pragma unroll
    for (int off = 1; off < 64; off <<= 1) {
        int u = __shfl_up(incl, off, 64);
        if (lane >= off) incl += u;
    }
    __shared__ int wsum[4];
    if (lane == 63) wsum[wid] = incl;
    __syncthreads();
    int woff = 0;
    for (int w = 0; w < wid; ++w) woff += wsum[w];
    int run = incl - tot + woff + pre;
#pragma unroll
    for (int k = 0; k < 4; ++k) {
        if (base + k < N) {
            rowptr[base + k] = run;
            dinv[base + k] = rsqrtf((float)d[k] + 1.0f);  // +1 self-loop
        }
        run += d[k];
    }
    if (b == gridDim.x - 1 && t == 255) rowptr[N] = E;
}

// ---- pass 4: fill csr_src within bucket (LDS cursors, 16KB window) ----
__global__ __launch_bounds__(256) void bucket_fill(const int* __restrict__ tmpP,
                                                   const int* __restrict__ rowptr,
                                                   int* __restrict__ csr_src, int N) {
    __shared__ int cur[256];
    int t = threadIdx.x, b = blockIdx.x;
    int base = b * 256;
    int node = base + t;
    if (node < N) cur[t] = rowptr[node];
    __syncthreads();
    int s = rowptr[base];
    int e = rowptr[min(base + 256, N)];
    for (int i = s + t; i < e; i += 256) {
        int ed = tmpP[i];
        int p = atomicAdd(&cur[ed & 255], 1);
        csr_src[p] = ed >> BSHIFT;
    }
}

// ---- MFMA GEMM: C[N,M](bf16) = A[N,128](fp32) @ W[128,M](fp32) ----
// block = 256 (4 waves), 64 rows/block; v_mfma_f32_16x16x32_bf16.
// A: lane holds A[m=lane&15][k=quad*8+j]; B: B[k=quad*8+j][n=lane&15];
// C/D: col=lane&15, row=quad*4+reg.
template <int M>
__global__ __launch_bounds__(256) void gemm_mfma(const float* __restrict__ A,
                                                 const float* __restrict__ W,
                                                 ushort* __restrict__ C, int N) {
    constexpr int WTS = 136;           // padded row stride (bf16): +8 kills conflicts
    __shared__ ushort WT[M * WTS];     // WT[n][k] = W[k][n]
    const int tid = threadIdx.x;
    for (int i = tid; i < 128 * (M / 4); i += 256) {
        int k = i / (M / 4);
        int n0 = (i % (M / 4)) * 4;
        float4 w = *(const float4*)&W[k * M + n0];
        WT[(n0 + 0) * WTS + k] = f2bf(w.x);
        WT[(n0 + 1) * WTS + k] = f2bf(w.y);
        WT[(n0 + 2) * WTS + k] = f2bf(w.z);
        WT[(n0 + 3) * WTS + k] = f2bf(w.w);
    }
    __syncthreads();

    const int wv = tid >> 6, lane = tid & 63;
    const int quad = lane >> 4, mrow = lane & 15;
    int arow_i = blockIdx.x * 64 + wv * 16 + mrow;
    if (arow_i >= N) arow_i = N - 1;   // clamp loads; stores guarded
    const float* arow = &A[(size_t)arow_i * 128];

    f32x4 acc[M / 16];
#pragma unroll
    for (int t = 0; t < M / 16; ++t) acc[t] = (f32x4){0.f, 0.f, 0.f, 0.f};

#pragma unroll
    for (int ks = 0; ks < 4; ++ks) {
        const int k0 = ks * 32 + quad * 8;
        float4 a0 = *(const float4*)&arow[k0];
        float4 a1 = *(const float4*)&arow[k0 + 4];
        bf16x8 af;
        af[0] = (short)f2bf(a0.x); af[1] = (short)f2bf(a0.y);
        af[2] = (short)f2bf(a0.z); af[3] = (short)f2bf(a0.w);
        af[4] = (short)f2bf(a1.x); af[5] = (short)f2bf(a1.y);
        af[6] = (short)f2bf(a1.z); af[7] = (short)f2bf(a1.w);
#pragma unroll
        for (int t = 0; t < M / 16; ++t) {
            int n = t * 16 + mrow;
            bf16x8 bfr = *(const bf16x8*)&WT[n * WTS + k0];
            acc[t] = __builtin_amdgcn_mfma_f32_16x16x32_bf16(af, bfr, acc[t], 0, 0, 0);
        }
    }

    const int orow0 = blockIdx.x * 64 + wv * 16 + quad * 4;
#pragma unroll
    for (int r = 0; r < 4; ++r) {
        int orow = orow0 + r;
        if (orow < N) {
#pragma unroll
            for (int t = 0; t < M / 16; ++t)
                C[(size_t)orow * M + t * 16 + mrow] = f2bf(acc[t][r]);
        }
    }
}

// ---- pull gather, bf16 table.  Q=D/8 lanes per row, G=64/Q edge slots. ----
template <int D, bool RELU>
__global__ __launch_bounds__(256) void gather_kernel(
    const ushort* __restrict__ h, const int* __restrict__ rowptr,
    const int* __restrict__ csr_src, const float* __restrict__ dinv,
    const float* __restrict__ bias, float* __restrict__ out, int N) {
    constexpr int Q = D / 8;   // lanes covering one row (16B bf16x8 per lane)
    constexpr int G = 64 / Q;  // concurrent edge slots per wave
    const int wid = threadIdx.x >> 6, lane = threadIdx.x & 63;
    const int node = blockIdx.x * 4 + wid;
    if (node >= N) return;
    const int g = lane / Q, q = lane % Q;
    const int qoff = q * 8;
    const int beg = rowptr[node], end = rowptr[node + 1];
    float acc[8] = {};

    for (int j = beg; j < end; j += 2 * G) {  // 2 independent chains in flight
        int e0 = j + g, e1 = j + G + g;
        {
            bool v = e0 < end;
            int s = v ? csr_src[e0] : node;
            float w = v ? dinv[s] : 0.0f;
            uint4 hv = *(const uint4*)&h[(size_t)s * D + qoff];
            acc[0] += w * bf_lo(hv.x); acc[1] += w * bf_hi(hv.x);
            acc[2] += w * bf_lo(hv.y); acc[3] += w * bf_hi(hv.y);
            acc[4] += w * bf_lo(hv.z); acc[5] += w * bf_hi(hv.z);
            acc[6] += w * bf_lo(hv.w); acc[7] += w * bf_hi(hv.w);
        }
        {
            bool v = e1 < end;
            int s = v ? csr_src[e1] : node;
            float w = v ? dinv[s] : 0.0f;
            uint4 hv = *(const uint4*)&h[(size_t)s * D + qoff];
            acc[0] += w * bf_lo(hv.x); acc[1] += w * bf_hi(hv.x);
            acc[2] += w * bf_lo(hv.y); acc[3] += w * bf_hi(hv.y);
            acc[4] += w * bf_lo(hv.z); acc[5] += w * bf_hi(hv.z);
            acc[6] += w * bf_lo(hv.w); acc[7] += w * bf_hi(hv.w);
        }
    }
#pragma unroll
    for (int m = Q; m < 64; m <<= 1)
#pragma unroll
        for (int k = 0; k < 8; ++k) acc[k] += __shfl_xor(acc[k], m, 64);

    const float di = dinv[node];
    {   // self-loop
        uint4 hv = *(const uint4*)&h[(size_t)node * D + qoff];
        acc[0] += di * bf_lo(hv.x); acc[1] += di * bf_hi(hv.x);
        acc[2] += di * bf_lo(hv.y); acc[3] += di * bf_hi(hv.y);
        acc[4] += di * bf_lo(hv.z); acc[5] += di * bf_hi(hv.z);
        acc[6] += di * bf_lo(hv.w); acc[7] += di * bf_hi(hv.w);
    }
    if (g == 0) {
        float4 b0 = *(const float4*)&bias[qoff];
        float4 b1 = *(const float4*)&bias[qoff + 4];
        float r[8] = {di * acc[0] + b0.x, di * acc[1] + b0.y,
                      di * acc[2] + b0.z, di * acc[3] + b0.w,
                      di * acc[4] + b1.x, di * acc[5] + b1.y,
                      di * acc[6] + b1.z, di * acc[7] + b1.w};
        if (RELU) {
#pragma unroll
            for (int k = 0; k < 8; ++k) r[k] = fmaxf(r[k], 0.0f);
        }
        *(float4*)&out[(size_t)node * D + qoff]     = make_float4(r[0], r[1], r[2], r[3]);
        *(float4*)&out[(size_t)node * D + qoff + 4] = make_float4(r[4], r[5], r[6], r[7]);
    }
}

extern "C" void kernel_launch(void* const* d_in, const int* in_sizes, int n_in,
                              void* d_out, int out_size, void* d_ws, size_t ws_size,
                              hipStream_t stream) {
    const float* x  = (const float*)d_in[0];
    const int*   ei = (const int*)d_in[1];
    const float* W1 = (const float*)d_in[2];
    const float* b1 = (const float*)d_in[3];
    const float* W2 = (const float*)d_in[4];
    const float* b2 = (const float*)d_in[5];
    float* out = (float*)d_out;

    const int N = in_sizes[0] / 128;
    const int E = in_sizes[1] / 2;
    const int* src = ei;
    const int* tgt = ei + E;

    const int nbk   = (N + 255) >> BSHIFT;   // buckets
    const int chunk = (E + NB - 1) / NB;     // edges per hist/scatter block
    const int Mc    = nbk * NB;              // counts length

    float* ws = (float*)d_ws;
    const size_t Np = (size_t)((N + 3) & ~3);
    float*  dinv    = ws;                            // Np
    int*    deg     = (int*)(ws + Np);               // Np
    int*    rowptr  = deg + Np;                      // Np+4
    int*    counts  = rowptr + Np + 4;               // MAXBK*NB (scanned in place)
    int*    bsum    = counts + MAXBK * NB;           // 128
    int*    csr_src = bsum + 128;                    // E
    int*    tmpP    = csr_src + E;                   // E packed (src<<8)|(tgt&255)
    ushort* h       = (ushort*)(tmpP + E);           // N*128 bf16 (reused as h2)
    float*  h1      = (float*)(h + (size_t)N * 128); // N*128 fp32
    ushort* h2      = h;

    const int nbc = (Mc + 1023) / 1024;
    const int nbd = (N + 1023) / 1024;

    // CSR build — no global atomics
    hist_kernel<<<NB, 256, 0, stream>>>(tgt, counts, E, chunk, nbk);
    scan_partial<<<nbc, 256, 0, stream>>>(counts, bsum, Mc);
    scan_final_counts<<<nbc, 256, 0, stream>>>(counts, bsum, Mc);
    bucket_scatter<<<NB, 256, 0, stream>>>(src, tgt, counts, tmpP, E, chunk, nbk);
    bucket_deg<<<nbk, 256, 0, stream>>>(tmpP, counts, deg, N, E, nbk);
    scan_final_deg<<<nbd, 256, 0, stream>>>(deg, counts, rowptr, dinv, N, E);
    bucket_fill<<<nbk, 256, 0, stream>>>(tmpP, rowptr, csr_src, N);

    // Layer 1
    gemm_mfma<128><<<(N + 63) / 64, 256, 0, stream>>>(x, W1, h, N);
    gather_kernel<128, true><<<(N + 3) / 4, 256, 0, stream>>>(
        h, rowptr, csr_src, dinv, b1, h1, N);

    // Layer 2
    gemm_mfma<64><<<(N + 63) / 64, 256, 0, stream>>>(h1, W2, h2, N);
    gather_kernel<64, false><<<(N + 3) / 4, 256, 0, stream>>>(
        h2, rowptr, csr_src, dinv, b2, out, N);
}

// Round 7
// 324.046 us; speedup vs baseline: 1.6101x; 1.0342x over previous
//
#include <hip/hip_runtime.h>

// ---------------------------------------------------------------------------
// 2-layer GCN forward, pull-mode, bf16 tables, MFMA GEMMs.
//
// R7: (a) h1 activation stored bf16 (gemm2 rounded it anyway -> bit-identical,
// halves gather1 WRITE + gemm2 FETCH).  (b) bucket_deg + deg-scan +
// bucket_fill fused into bucket_finish: bucket edges staged in LDS once,
// per-node count -> block scan -> rowptr/dinv -> csr fill.  9 dispatches,
// no global atomics, no memsets.
//
// ws (4B units): dinv[Np] rowptr[Np+4] counts[MAXBK*NB] bsum[128]
//   csr_src[E] tmpP[E] | h ushort[N*128] (reused as h2 ushort[N*64])
//   | h1 ushort[N*128]
// ---------------------------------------------------------------------------

typedef unsigned int uint;
typedef unsigned short ushort;
typedef __attribute__((ext_vector_type(8))) short bf16x8;
typedef __attribute__((ext_vector_type(8))) ushort u16x8;
typedef __attribute__((ext_vector_type(4))) float f32x4;

#define BSHIFT 8          // nodes per bucket = 256
#define MAXBK  512        // max buckets (N <= 131072)
#define NB     256        // hist/scatter blocks
#define CAP    8192       // LDS-staged edges per bucket (avg ~4096, sigma ~64)

__device__ inline ushort f2bf(float f) {
    uint u = __float_as_uint(f);
    return (ushort)((u + 0x7fffu + ((u >> 16) & 1u)) >> 16);  // RNE
}
__device__ inline float bf_lo(uint u) { return __uint_as_float(u << 16); }
__device__ inline float bf_hi(uint u) { return __uint_as_float(u & 0xffff0000u); }

// ---- pass 1: per-block bucket histogram (LDS atomics only) ----
__global__ __launch_bounds__(256) void hist_kernel(const int* __restrict__ tgt,
                                                   int* __restrict__ counts,
                                                   int E, int chunk, int nbk) {
    __shared__ int hist[MAXBK];
    int t = threadIdx.x, b = blockIdx.x;
    for (int i = t; i < nbk; i += 256) hist[i] = 0;
    __syncthreads();
    int s = b * chunk, e = min(E, s + chunk);
    for (int i = s + t; i < e; i += 256) atomicAdd(&hist[tgt[i] >> BSHIFT], 1);
    __syncthreads();
    for (int i = t; i < nbk; i += 256) counts[i * NB + b] = hist[i];
}

// ---- scan step 1: per-1024 partial sums of counts ----
__global__ __launch_bounds__(256) void scan_partial(const int* __restrict__ in,
                                                    int* __restrict__ bsum, int M) {
    int t = threadIdx.x, b = blockIdx.x;
    int base = b * 1024 + t * 4;
    int s = 0;
#pragma unroll
    for (int k = 0; k < 4; ++k) s += (base + k < M) ? in[base + k] : 0;
#pragma unroll
    for (int off = 32; off > 0; off >>= 1) s += __shfl_down(s, off, 64);
    __shared__ int ws[4];
    if ((t & 63) == 0) ws[t >> 6] = s;
    __syncthreads();
    if (t == 0) bsum[b] = ws[0] + ws[1] + ws[2] + ws[3];
}

// ---- scan step 2: exclusive scan of counts in place (bsum prefix fused) ----
__global__ __launch_bounds__(256) void scan_final_counts(int* __restrict__ counts,
                                                         const int* __restrict__ bsum,
                                                         int M) {
    int t = threadIdx.x, b = blockIdx.x;
    int lane = t & 63, wid = t >> 6;
    int p = 0;
    for (int i = t; i < b; i += 256) p += bsum[i];
#pragma unroll
    for (int off = 32; off > 0; off >>= 1) p += __shfl_down(p, off, 64);
    __shared__ int ps[4];
    if (lane == 0) ps[wid] = p;
    __syncthreads();
    int pre = ps[0] + ps[1] + ps[2] + ps[3];

    int base = b * 1024 + t * 4;
    int d[4];
#pragma unroll
    for (int k = 0; k < 4; ++k) d[k] = (base + k < M) ? counts[base + k] : 0;
    int tot = d[0] + d[1] + d[2] + d[3];
    int incl = tot;
#pragma unroll
    for (int off = 1; off < 64; off <<= 1) {
        int u = __shfl_up(incl, off, 64);
        if (lane >= off) incl += u;
    }
    __shared__ int wsum[4];
    if (lane == 63) wsum[wid] = incl;
    __syncthreads();
    int woff = 0;
    for (int w = 0; w < wid; ++w) woff += wsum[w];
    int run = incl - tot + woff + pre;
#pragma unroll
    for (int k = 0; k < 4; ++k) {
        if (base + k < M) counts[base + k] = run;
        run += d[k];
    }
}

// ---- pass 2: scatter edges into bucket-contiguous packed tmp ----
__global__ __launch_bounds__(256) void bucket_scatter(const int* __restrict__ src,
                                                      const int* __restrict__ tgt,
                                                      const int* __restrict__ offsets,
                                                      int* __restrict__ tmpP,
                                                      int E, int chunk, int nbk) {
    __shared__ int cur[MAXBK];
    int t = threadIdx.x, b = blockIdx.x;
    for (int i = t; i < nbk; i += 256) cur[i] = offsets[i * NB + b];
    __syncthreads();
    int s = b * chunk, e = min(E, s + chunk);
    for (int i = s + t; i < e; i += 256) {
        int tg = tgt[i];
        int p = atomicAdd(&cur[tg >> BSHIFT], 1);
        tmpP[p] = (src[i] << BSHIFT) | (tg & 255);
    }
}

// ---- pass 3 (fused): per-bucket deg count + scan + rowptr/dinv + csr fill ----
__global__ __launch_bounds__(256) void bucket_finish(const int* __restrict__ tmpP,
                                                     const int* __restrict__ offsets,
                                                     int* __restrict__ rowptr,
                                                     float* __restrict__ dinv,
                                                     int* __restrict__ csr_src,
                                                     int N, int E, int nbk) {
    __shared__ int stage[CAP];
    __shared__ int cnt[256];
    __shared__ int wsum[4];
    int t = threadIdx.x, b = blockIdx.x;
    cnt[t] = 0;
    __syncthreads();
    int s = offsets[b * NB];
    int e = (b + 1 < nbk) ? offsets[(b + 1) * NB] : E;
    int m = e - s;
    // phase A: read bucket edges once; stage in LDS; count per node
    for (int i = t; i < m; i += 256) {
        int ed = tmpP[s + i];
        if (i < CAP) stage[i] = ed;
        atomicAdd(&cnt[ed & 255], 1);
    }
    __syncthreads();
    // phase B: exclusive scan of cnt[256]
    int lane = t & 63, wid = t >> 6;
    int d = cnt[t];
    int incl = d;
#pragma unroll
    for (int off = 1; off < 64; off <<= 1) {
        int u = __shfl_up(incl, off, 64);
        if (lane >= off) incl += u;
    }
    if (lane == 63) wsum[wid] = incl;
    __syncthreads();
    int woff = 0;
    for (int w = 0; w < wid; ++w) woff += wsum[w];
    int excl = s + incl - d + woff;   // global CSR offset for this node
    int node = b * 256 + t;
    if (node < N) {
        rowptr[node] = excl;
        dinv[node] = rsqrtf((float)d + 1.0f);  // +1 self-loop
    }
    if (b == nbk - 1 && t == 255) rowptr[N] = E;
    cnt[t] = excl;  // reuse as cursor (all reads of cnt are done: pre-wsum-sync)
    __syncthreads();
    // phase C: fill csr_src (LDS stage; global fallback past CAP)
    for (int i = t; i < m; i += 256) {
        int ed = (i < CAP) ? stage[i] : tmpP[s + i];
        int p = atomicAdd(&cnt[ed & 255], 1);
        csr_src[p] = ed >> BSHIFT;
    }
}

// ---- MFMA GEMM: C[N,M](bf16) = A[N,128](AT) @ W[128,M](fp32) ----
// block = 256 (4 waves), 64 rows/block; v_mfma_f32_16x16x32_bf16.
// AT = float (convert in-flight) or ushort (bf16, load direct).
template <int M, typename AT>
__global__ __launch_bounds__(256) void gemm_mfma(const AT* __restrict__ A,
                                                 const float* __restrict__ W,
                                                 ushort* __restrict__ C, int N) {
    constexpr int WTS = 136;           // padded row stride (bf16): +8 kills conflicts
    __shared__ ushort WT[M * WTS];     // WT[n][k] = W[k][n]
    const int tid = threadIdx.x;
    for (int i = tid; i < 128 * (M / 4); i += 256) {
        int k = i / (M / 4);
        int n0 = (i % (M / 4)) * 4;
        float4 w = *(const float4*)&W[k * M + n0];
        WT[(n0 + 0) * WTS + k] = f2bf(w.x);
        WT[(n0 + 1) * WTS + k] = f2bf(w.y);
        WT[(n0 + 2) * WTS + k] = f2bf(w.z);
        WT[(n0 + 3) * WTS + k] = f2bf(w.w);
    }
    __syncthreads();

    const int wv = tid >> 6, lane = tid & 63;
    const int quad = lane >> 4, mrow = lane & 15;
    int arow_i = blockIdx.x * 64 + wv * 16 + mrow;
    if (arow_i >= N) arow_i = N - 1;   // clamp loads; stores guarded
    const AT* arow = &A[(size_t)arow_i * 128];

    f32x4 acc[M / 16];
#pragma unroll
    for (int t = 0; t < M / 16; ++t) acc[t] = (f32x4){0.f, 0.f, 0.f, 0.f};

#pragma unroll
    for (int ks = 0; ks < 4; ++ks) {
        const int k0 = ks * 32 + quad * 8;
        bf16x8 af;
        if constexpr (sizeof(AT) == 4) {
            float4 a0 = *(const float4*)&arow[k0];
            float4 a1 = *(const float4*)&arow[k0 + 4];
            af[0] = (short)f2bf(a0.x); af[1] = (short)f2bf(a0.y);
            af[2] = (short)f2bf(a0.z); af[3] = (short)f2bf(a0.w);
            af[4] = (short)f2bf(a1.x); af[5] = (short)f2bf(a1.y);
            af[6] = (short)f2bf(a1.z); af[7] = (short)f2bf(a1.w);
        } else {
            af = *(const bf16x8*)&arow[k0];
        }
#pragma unroll
        for (int t = 0; t < M / 16; ++t) {
            int n = t * 16 + mrow;
            bf16x8 bfr = *(const bf16x8*)&WT[n * WTS + k0];
            acc[t] = __builtin_amdgcn_mfma_f32_16x16x32_bf16(af, bfr, acc[t], 0, 0, 0);
        }
    }

    const int orow0 = blockIdx.x * 64 + wv * 16 + quad * 4;
#pragma unroll
    for (int r = 0; r < 4; ++r) {
        int orow = orow0 + r;
        if (orow < N) {
#pragma unroll
            for (int t = 0; t < M / 16; ++t)
                C[(size_t)orow * M + t * 16 + mrow] = f2bf(acc[t][r]);
        }
    }
}

// ---- pull gather, bf16 table.  Q=D/8 lanes per row, G=64/Q edge slots.
// OUTBF: write bf16 activation (layer 1); else fp32 (final output).
template <int D, bool RELU, bool OUTBF>
__global__ __launch_bounds__(256) void gather_kernel(
    const ushort* __restrict__ h, const int* __restrict__ rowptr,
    const int* __restrict__ csr_src, const float* __restrict__ dinv,
    const float* __restrict__ bias, void* __restrict__ outv, int N) {
    constexpr int Q = D / 8;   // lanes covering one row (16B bf16x8 per lane)
    constexpr int G = 64 / Q;  // concurrent edge slots per wave
    const int wid = threadIdx.x >> 6, lane = threadIdx.x & 63;
    const int node = blockIdx.x * 4 + wid;
    if (node >= N) return;
    const int g = lane / Q, q = lane % Q;
    const int qoff = q * 8;
    const int beg = rowptr[node], end = rowptr[node + 1];
    float acc[8] = {};

    for (int j = beg; j < end; j += 2 * G) {  // 2 independent chains in flight
        int e0 = j + g, e1 = j + G + g;
        {
            bool v = e0 < end;
            int s = v ? csr_src[e0] : node;
            float w = v ? dinv[s] : 0.0f;
            uint4 hv = *(const uint4*)&h[(size_t)s * D + qoff];
            acc[0] += w * bf_lo(hv.x); acc[1] += w * bf_hi(hv.x);
            acc[2] += w * bf_lo(hv.y); acc[3] += w * bf_hi(hv.y);
            acc[4] += w * bf_lo(hv.z); acc[5] += w * bf_hi(hv.z);
            acc[6] += w * bf_lo(hv.w); acc[7] += w * bf_hi(hv.w);
        }
        {
            bool v = e1 < end;
            int s = v ? csr_src[e1] : node;
            float w = v ? dinv[s] : 0.0f;
            uint4 hv = *(const uint4*)&h[(size_t)s * D + qoff];
            acc[0] += w * bf_lo(hv.x); acc[1] += w * bf_hi(hv.x);
            acc[2] += w * bf_lo(hv.y); acc[3] += w * bf_hi(hv.y);
            acc[4] += w * bf_lo(hv.z); acc[5] += w * bf_hi(hv.z);
            acc[6] += w * bf_lo(hv.w); acc[7] += w * bf_hi(hv.w);
        }
    }
#pragma unroll
    for (int m = Q; m < 64; m <<= 1)
#pragma unroll
        for (int k = 0; k < 8; ++k) acc[k] += __shfl_xor(acc[k], m, 64);

    const float di = dinv[node];
    {   // self-loop
        uint4 hv = *(const uint4*)&h[(size_t)node * D + qoff];
        acc[0] += di * bf_lo(hv.x); acc[1] += di * bf_hi(hv.x);
        acc[2] += di * bf_lo(hv.y); acc[3] += di * bf_hi(hv.y);
        acc[4] += di * bf_lo(hv.z); acc[5] += di * bf_hi(hv.z);
        acc[6] += di * bf_lo(hv.w); acc[7] += di * bf_hi(hv.w);
    }
    if (g == 0) {
        float4 b0 = *(const float4*)&bias[qoff];
        float4 b1 = *(const float4*)&bias[qoff + 4];
        float r[8] = {di * acc[0] + b0.x, di * acc[1] + b0.y,
                      di * acc[2] + b0.z, di * acc[3] + b0.w,
                      di * acc[4] + b1.x, di * acc[5] + b1.y,
                      di * acc[6] + b1.z, di * acc[7] + b1.w};
        if (RELU) {
#pragma unroll
            for (int k = 0; k < 8; ++k) r[k] = fmaxf(r[k], 0.0f);
        }
        if constexpr (OUTBF) {
            ushort* out = (ushort*)outv;
            u16x8 o;
#pragma unroll
            for (int k = 0; k < 8; ++k) o[k] = f2bf(r[k]);
            *(u16x8*)&out[(size_t)node * D + qoff] = o;
        } else {
            float* out = (float*)outv;
            *(float4*)&out[(size_t)node * D + qoff]     = make_float4(r[0], r[1], r[2], r[3]);
            *(float4*)&out[(size_t)node * D + qoff + 4] = make_float4(r[4], r[5], r[6], r[7]);
        }
    }
}

extern "C" void kernel_launch(void* const* d_in, const int* in_sizes, int n_in,
                              void* d_out, int out_size, void* d_ws, size_t ws_size,
                              hipStream_t stream) {
    const float* x  = (const float*)d_in[0];
    const int*   ei = (const int*)d_in[1];
    const float* W1 = (const float*)d_in[2];
    const float* b1 = (const float*)d_in[3];
    const float* W2 = (const float*)d_in[4];
    const float* b2 = (const float*)d_in[5];
    float* out = (float*)d_out;

    const int N = in_sizes[0] / 128;
    const int E = in_sizes[1] / 2;
    const int* src = ei;
    const int* tgt = ei + E;

    const int nbk   = (N + 255) >> BSHIFT;   // buckets
    const int chunk = (E + NB - 1) / NB;     // edges per hist/scatter block
    const int Mc    = nbk * NB;              // counts length

    float* ws = (float*)d_ws;
    const size_t Np = (size_t)((N + 3) & ~3);
    float*  dinv    = ws;                            // Np
    int*    rowptr  = (int*)(ws + Np);               // Np+4
    int*    counts  = rowptr + Np + 4;               // MAXBK*NB (scanned in place)
    int*    bsum    = counts + MAXBK * NB;           // 128
    int*    csr_src = bsum + 128;                    // E
    int*    tmpP    = csr_src + E;                   // E packed (src<<8)|(tgt&255)
    ushort* h       = (ushort*)(tmpP + E);           // N*128 bf16 (reused as h2)
    ushort* h1      = h + (size_t)N * 128;           // N*128 bf16
    ushort* h2      = h;

    const int nbc = (Mc + 1023) / 1024;

    // CSR build — no global atomics, no memsets
    hist_kernel<<<NB, 256, 0, stream>>>(tgt, counts, E, chunk, nbk);
    scan_partial<<<nbc, 256, 0, stream>>>(counts, bsum, Mc);
    scan_final_counts<<<nbc, 256, 0, stream>>>(counts, bsum, Mc);
    bucket_scatter<<<NB, 256, 0, stream>>>(src, tgt, counts, tmpP, E, chunk, nbk);
    bucket_finish<<<nbk, 256, 0, stream>>>(tmpP, counts, rowptr, dinv, csr_src, N, E, nbk);

    // Layer 1
    gemm_mfma<128, float><<<(N + 63) / 64, 256, 0, stream>>>(x, W1, h, N);
    gather_kernel<128, true, true><<<(N + 3) / 4, 256, 0, stream>>>(
        h, rowptr, csr_src, dinv, b1, h1, N);

    // Layer 2
    gemm_mfma<64, ushort><<<(N + 63) / 64, 256, 0, stream>>>(h1, W2, h2, N);
    gather_kernel<64, false, false><<<(N + 3) / 4, 256, 0, stream>>>(
        h2, rowptr, csr_src, dinv, b2, out, N);
}